// Round 2
// baseline (10518.489 us; speedup 1.0000x reference)
//
#include <hip/hip_runtime.h>
#include <cstdint>
#include <cstddef>

#define NROWS 16
#define NTHR  256
#define HSZ   256
#define ESZ   64
#define VSZ   26
#define NCOMP 15
#define BATCH 65536

// ---------------- threefry2x32 (exact JAX semantics) ----------------
__device__ __forceinline__ uint32_t rotl32(uint32_t v, int d) {
  return (v << d) | (v >> (32 - d));
}

__device__ __forceinline__ void tf2x32(uint32_t kA, uint32_t kB,
                                       uint32_t& x0, uint32_t& x1) {
  uint32_t kC = kA ^ kB ^ 0x1BD11BDAu;
  x0 += kA; x1 += kB;
#define TFR(r) { x0 += x1; x1 = rotl32(x1, r); x1 ^= x0; }
  TFR(13) TFR(15) TFR(26) TFR(6)
  x0 += kB; x1 += kC + 1u;
  TFR(17) TFR(29) TFR(16) TFR(24)
  x0 += kC; x1 += kA + 2u;
  TFR(13) TFR(15) TFR(26) TFR(6)
  x0 += kA; x1 += kB + 3u;
  TFR(17) TFR(29) TFR(16) TFR(24)
  x0 += kB; x1 += kC + 4u;
  TFR(13) TFR(15) TFR(26) TFR(6)
  x0 += kC; x1 += kA + 5u;
#undef TFR
}

// ---------------- XLA-matching transcendentals ----------------
__device__ __forceinline__ float xla_tanh(float x) {
  #pragma clang fp contract(off)
  float ax = fabsf(x);
  float xc = fminf(fmaxf(x, -7.90531110763549805f), 7.90531110763549805f);
  float x2 = xc * xc;
  float nu = -2.76076847742355e-16f;
  nu = x2 * nu + 2.00018790482477e-13f;
  nu = x2 * nu + -8.60467152213735e-11f;
  nu = x2 * nu + 5.12229709037114e-08f;
  nu = x2 * nu + 1.48572235717979e-05f;
  nu = x2 * nu + 6.37261928875436e-04f;
  nu = x2 * nu + 4.89352455891786e-03f;
  nu = xc * nu;
  float de = 1.19825839466702e-06f;
  de = x2 * de + 1.18534705686654e-04f;
  de = x2 * de + 2.26843463243900e-03f;
  de = x2 * de + 4.89352518554385e-03f;
  float r = nu / de;
  return (ax < 0.0004f) ? x : r;
}

__device__ __forceinline__ float xla_sigmoid(float x) {
  #pragma clang fp contract(off)
  return 0.5f + 0.5f * xla_tanh(0.5f * x);
}

__device__ __forceinline__ float xla_log(float x) {
  #pragma clang fp contract(off)
  uint32_t bits = __float_as_uint(x);
  int ei = (int)(bits >> 23) - 126;
  float m = __uint_as_float((bits & 0x007FFFFFu) | 0x3F000000u);  // [0.5,1)
  bool lt = m < 0.707106781186547524f;
  float ee = (float)ei - (lt ? 1.0f : 0.0f);
  float mm = (m - 1.0f) + (lt ? m : 0.0f);
  float x2 = mm * mm;
  float x3 = x2 * mm;
  float y  = __builtin_fmaf(7.0376836292E-2f,  mm, -1.1514610310E-1f);
  float y1 = __builtin_fmaf(-1.2420140846E-1f, mm,  1.4249322787E-1f);
  float y2 = __builtin_fmaf(2.0000714765E-1f,  mm, -2.4999993993E-1f);
  y  = __builtin_fmaf(y,  mm, 1.1676998740E-1f);
  y1 = __builtin_fmaf(y1, mm, -1.6668057665E-1f);
  y2 = __builtin_fmaf(y2, mm, 3.3333331174E-1f);
  y  = __builtin_fmaf(y, x3, y1);
  y  = __builtin_fmaf(y, x3, y2);
  y  = y * x3;
  float t1 = ee * -2.12194440e-4f;
  float t2 = 0.5f * x2;
  y  = y + t1;
  mm = mm - t2;
  float t3 = ee * 0.693359375f;
  mm = mm + y;
  mm = mm + t3;
  return mm;
}

// ---------------- FMA chains (k ascending => bit-exact XLA order) ----------------
// Original layout: W[k*1024 + gate*256 + u]
__device__ __forceinline__ void chain4(float* aI, float* aF, float* aG, float* aO,
                                       const float* lds, const float* W, int u, int nk) {
  const float* w = W + u;
  for (int k = 0; k < nk; ++k) {
    float wI = w[0], wF = w[256], wG = w[512], wO = w[768];
    w += 1024;
    #pragma unroll
    for (int rq = 0; rq < 4; ++rq) {
      float hv[4];
      *(float4*)hv = *(const float4*)(lds + k * 16 + rq * 4);
      #pragma unroll
      for (int j = 0; j < 4; ++j) {
        int r = rq * 4 + j;
        aI[r] = __builtin_fmaf(hv[j], wI, aI[r]);
        aF[r] = __builtin_fmaf(hv[j], wF, aF[r]);
        aG[r] = __builtin_fmaf(hv[j], wG, aG[r]);
        aO[r] = __builtin_fmaf(hv[j], wO, aO[r]);
      }
    }
  }
}

// Repacked layout: W4[k*256 + u] = {wI,wF,wG,wO} for (k,u)
__device__ __forceinline__ void chain4v(float* aI, float* aF, float* aG, float* aO,
                                        const float* lds, const float4* W4, int u, int nk) {
  const float4* w = W4 + u;
  #pragma unroll 2
  for (int k = 0; k < nk; ++k) {
    float4 wv = w[(size_t)k * 256];
    #pragma unroll
    for (int rq = 0; rq < 4; ++rq) {
      float hv[4];
      *(float4*)hv = *(const float4*)(lds + k * 16 + rq * 4);
      #pragma unroll
      for (int j = 0; j < 4; ++j) {
        int r = rq * 4 + j;
        aI[r] = __builtin_fmaf(hv[j], wv.x, aI[r]);
        aF[r] = __builtin_fmaf(hv[j], wv.y, aF[r]);
        aG[r] = __builtin_fmaf(hv[j], wv.z, aG[r]);
        aO[r] = __builtin_fmaf(hv[j], wv.w, aO[r]);
      }
    }
  }
}

// One-time weight repack: [k][gate*256+u] -> [k][u][gate] float4
__global__ void repack_w(const float* __restrict__ W, float4* __restrict__ W4, int n) {
  int i = blockIdx.x * blockDim.x + threadIdx.x;
  if (i < n) {
    int k = i >> 8, u = i & 255;
    const float* src = W + (size_t)k * 1024 + u;
    W4[i] = make_float4(src[0], src[256], src[512], src[768]);
  }
}

__global__ __launch_bounds__(NTHR, 2) void belief_main(
    const float* __restrict__ ctx, const float* __restrict__ embed,
    const float* __restrict__ start_e, const float* __restrict__ Wp,
    const float* __restrict__ bp, const float* __restrict__ Wi,
    const float* __restrict__ Wh, const float* __restrict__ bh,
    const float* __restrict__ Wo, const float* __restrict__ bo,
    const int* __restrict__ seedp, float* __restrict__ out,
    const float4* __restrict__ Wi4, const float4* __restrict__ Wh4, int packed) {
  __shared__ __align__(16) float hT[HSZ * NROWS];      // h transposed [k][r]
  __shared__ __align__(16) float ctxT[HSZ * NROWS];    // ctx transposed [m][r]
  __shared__ __align__(16) float prevT[ESZ * NROWS];   // prev embed [e][r]
  __shared__ __align__(16) float woLds[HSZ * VSZ];
  __shared__ float boLds[VSZ];
  __shared__ float scores[NROWS * VSZ];
  __shared__ int tokLds[NROWS];
  __shared__ uint32_t skLds[NCOMP * 2];

  const int t = threadIdx.x;
  const int b0 = blockIdx.x * NROWS;

  // ---- stage LDS ----
  #pragma unroll
  for (int r = 0; r < NROWS; ++r)
    ctxT[t * NROWS + r] = ctx[(size_t)(b0 + r) * HSZ + t];
  for (int i = t; i < HSZ * VSZ; i += NTHR) woLds[i] = Wo[i];
  if (t < VSZ) boLds[t] = bo[t];
  for (int i = t; i < ESZ * NROWS; i += NTHR) prevT[i] = start_e[i >> 4];
  if (t < NCOMP) {
    uint32_t x0 = 0u, x1 = (uint32_t)t;   // partitionable split: tf(key, 0, t)
    tf2x32(0u, (uint32_t)seedp[0], x0, x1);
    skLds[2 * t] = x0; skLds[2 * t + 1] = x1;
  }
  __syncthreads();

  // ---- h0 = tanh(ctx @ Wp + bp), thread t owns hidden unit t, rows 0..15 ----
  float c[NROWS];
  {
    float acc[NROWS];
    #pragma unroll
    for (int r = 0; r < NROWS; ++r) acc[r] = 0.0f;
    const float* wp = Wp + t;
    for (int m = 0; m < HSZ; ++m) {
      float w = wp[(size_t)m * HSZ];
      #pragma unroll
      for (int rq = 0; rq < 4; ++rq) {
        float hv[4];
        *(float4*)hv = *(const float4*)&ctxT[m * NROWS + rq * 4];
        #pragma unroll
        for (int j = 0; j < 4; ++j)
          acc[rq * 4 + j] = __builtin_fmaf(hv[j], w, acc[rq * 4 + j]);
      }
    }
    float bpv = bp[t];
    #pragma unroll
    for (int r = 0; r < NROWS; ++r) {
      float s = acc[r] + bpv;
      hT[t * NROWS + r] = xla_tanh(s);
      c[r] = 0.0f;
    }
  }

  // ---- ctx @ Wi[0:256] prefix, kept in REGISTERS across all steps ----
  float pI[16], pF[16], pG[16], pO[16];
  #pragma unroll
  for (int r = 0; r < 16; ++r) { pI[r] = 0.f; pF[r] = 0.f; pG[r] = 0.f; pO[r] = 0.f; }
  if (packed) chain4v(pI, pF, pG, pO, ctxT, Wi4, t, HSZ);
  else        chain4 (pI, pF, pG, pO, ctxT, Wi,  t, HSZ);
  __syncthreads();

  const float bhI = bh[t], bhF = bh[256 + t], bhG = bh[512 + t], bhO = bh[768 + t];
  const float*  WiP  = Wi  + (size_t)HSZ * 1024;  // prev-embed rows (raw)
  const float4* WiP4 = Wi4 + (size_t)HSZ * 256;   // prev-embed rows (packed)

  for (int s = 0; s < NCOMP; ++s) {
    // dotA = x @ Wi: resume from register prefix, continue over prev rows
    float aI[16], aF[16], aG[16], aO[16];
    #pragma unroll
    for (int r = 0; r < 16; ++r) { aI[r] = pI[r]; aF[r] = pF[r]; aG[r] = pG[r]; aO[r] = pO[r]; }
    if (packed) chain4v(aI, aF, aG, aO, prevT, WiP4, t, ESZ);
    else        chain4 (aI, aF, aG, aO, prevT, WiP,  t, ESZ);

    // dotB = h @ Wh (separate accumulator; added afterwards like XLA)
    float bI[16], bF[16], bG[16], bO[16];
    #pragma unroll
    for (int r = 0; r < 16; ++r) { bI[r] = 0.f; bF[r] = 0.f; bG[r] = 0.f; bO[r] = 0.f; }
    if (packed) chain4v(bI, bF, bG, bO, hT, Wh4, t, HSZ);
    else        chain4 (bI, bF, bG, bO, hT, Wh,  t, HSZ);

    // pointwise LSTM cell (plain mul/add, XLA-style no contraction)
    float hnew[16];
    {
      #pragma clang fp contract(off)
      #pragma unroll
      for (int r = 0; r < 16; ++r) {
        float gi = (aI[r] + bI[r]) + bhI;
        float gf = (aF[r] + bF[r]) + bhF;
        float gg = (aG[r] + bG[r]) + bhG;
        float go = (aO[r] + bO[r]) + bhO;
        float si = xla_sigmoid(gi);
        float sf = xla_sigmoid(gf);
        float tg = xla_tanh(gg);
        float so = xla_sigmoid(go);
        float cn = sf * c[r] + si * tg;
        c[r] = cn;
        hnew[r] = so * xla_tanh(cn);
      }
    }
    __syncthreads();                       // all waves done reading hT/prevT
    #pragma unroll
    for (int r = 0; r < 16; ++r) hT[t * NROWS + r] = hnew[r];
    __syncthreads();

    // logits + gumbel + scores
    uint32_t sk0 = skLds[2 * s], sk1 = skLds[2 * s + 1];
    for (int p = t; p < NROWS * VSZ; p += NTHR) {
      int r = p / VSZ, v = p - r * VSZ;
      float acc = 0.0f;
      for (int k = 0; k < HSZ; ++k)
        acc = __builtin_fmaf(hT[k * NROWS + r], woLds[k * VSZ + v], acc);
      float logit = acc + boLds[v];
      out[(size_t)(b0 + r) * (NCOMP * VSZ) + s * VSZ + v] = logit;

      uint32_t n = (uint32_t)(b0 + r) * VSZ + (uint32_t)v;
      uint32_t x0 = 0u, x1 = n;
      tf2x32(sk0, sk1, x0, x1);
      uint32_t rb = x0 ^ x1;
      float f = __uint_as_float((rb >> 9) | 0x3F800000u) - 1.0f;
      float uu;
      {
        #pragma clang fp contract(off)
        uu = f + 1.17549435082228751e-38f;
      }
      uu = fmaxf(1.17549435082228751e-38f, uu);
      float l1 = xla_log(uu);
      float g = -xla_log(-l1);
      {
        #pragma clang fp contract(off)
        scores[r * VSZ + v] = g + logit;
      }
    }
    __syncthreads();

    // argmax (first max index), write sample, pick next embedding
    if (t < NROWS) {
      float mbest = scores[t * VSZ];
      int ibest = 0;
      for (int v = 1; v < VSZ; ++v) {
        float sc = scores[t * VSZ + v];
        if (sc > mbest) { mbest = sc; ibest = v; }
      }
      tokLds[t] = ibest;
      out[(size_t)BATCH * (NCOMP * VSZ) + (size_t)(b0 + t) * NCOMP + s] = (float)ibest;
    }
    __syncthreads();
    if (s < NCOMP - 1) {
      for (int i = t; i < ESZ * NROWS; i += NTHR) {
        int e = i >> 4, r = i & 15;
        prevT[i] = embed[tokLds[r] * ESZ + e];
      }
    }
    __syncthreads();
  }
}

extern "C" void kernel_launch(void* const* d_in, const int* in_sizes, int n_in,
                              void* d_out, int out_size, void* d_ws, size_t ws_size,
                              hipStream_t stream) {
  const float* ctx     = (const float*)d_in[0];
  const float* embed   = (const float*)d_in[1];
  const float* start_e = (const float*)d_in[2];
  const float* Wp      = (const float*)d_in[3];
  const float* bp      = (const float*)d_in[4];
  const float* Wi      = (const float*)d_in[5];
  const float* Wh      = (const float*)d_in[6];
  const float* bh      = (const float*)d_in[7];
  const float* Wo      = (const float*)d_in[8];
  const float* bo      = (const float*)d_in[9];
  const int*   seedp   = (const int*)d_in[10];
  float* out = (float*)d_out;

  // Workspace layout: Wi4 (320*256 float4) then Wh4 (256*256 float4)
  size_t wi4_elems = (size_t)(HSZ + ESZ) * 256;
  size_t wh4_elems = (size_t)HSZ * 256;
  size_t need = (wi4_elems + wh4_elems) * sizeof(float4);
  int packed = (d_ws != nullptr && ws_size >= need) ? 1 : 0;
  float4* Wi4 = (float4*)d_ws;
  float4* Wh4 = Wi4 + wi4_elems;

  if (packed) {
    int nWi = (int)wi4_elems, nWh = (int)wh4_elems;
    hipLaunchKernelGGL(repack_w, dim3((nWi + 255) / 256), dim3(256), 0, stream, Wi, Wi4, nWi);
    hipLaunchKernelGGL(repack_w, dim3((nWh + 255) / 256), dim3(256), 0, stream, Wh, Wh4, nWh);
  }

  hipLaunchKernelGGL(belief_main, dim3(BATCH / NROWS), dim3(NTHR), 0, stream,
                     ctx, embed, start_e, Wp, bp, Wi, Wh, bh, Wo, bo, seedp,
                     out, Wi4, Wh4, packed);
}